// Round 13
// baseline (579.471 us; speedup 1.0000x reference)
//
#include <hip/hip_runtime.h>

#define NGRAPHS 256
#define GBUCKET 256
#define CAP 8192          // per-bucket pair capacity; E/G = 6250 expected, >20 sigma margin
#define BUCKET_BLOCKS 512
#define MAXE 16           // per-thread edge cache (E up to 2.09M)

typedef unsigned long long u64;

// ---------------- pass 1: counting-sort edges into 256 dst-range buckets ----------------

__global__ __launch_bounds__(256) void k_bucket(const int* __restrict__ src,
                                                const int* __restrict__ dst,
                                                int E, int N,
                                                int* __restrict__ bcur,
                                                u64* __restrict__ bpair) {
    __shared__ int hist[GBUCKET], base[GBUCKET], cur[GBUCKET];
    int t = threadIdx.x;
    int chunk = (E + gridDim.x - 1) / gridDim.x;
    int s0 = blockIdx.x * chunk;
    int s1 = s0 + chunk; if (s1 > E) s1 = E;
    if (s0 >= E) return;
    for (int i = t; i < GBUCKET; i += 256) hist[i] = 0;
    __syncthreads();

    int dcache[MAXE], scache[MAXE], bcache[MAXE];
#pragma unroll
    for (int u = 0; u < MAXE; ++u) {
        int e = s0 + t + u * 256;
        bool ok = e < s1;
        int d = ok ? __builtin_nontemporal_load(&dst[e]) : -1;
        int s = ok ? __builtin_nontemporal_load(&src[e]) : 0;
        int bkt = ok ? (int)(((long long)d * GBUCKET) / N) : -1;
        dcache[u] = d; scache[u] = s; bcache[u] = bkt;
        if (ok) atomicAdd(&hist[bkt], 1);
    }
    __syncthreads();
    for (int i = t; i < GBUCKET; i += 256) {
        base[i] = atomicAdd(&bcur[i], hist[i]);   // block-level reservation
        cur[i] = 0;
    }
    __syncthreads();
#pragma unroll
    for (int u = 0; u < MAXE; ++u) {
        int bkt = bcache[u];
        if (bkt >= 0) {
            int off = atomicAdd(&cur[bkt], 1);    // LDS atomic
            u64 p = ((u64)(unsigned)dcache[u] << 32) | (u64)(unsigned)scache[u];
            __builtin_nontemporal_store(p, &bpair[(size_t)bkt * CAP + base[bkt] + off]);
        }
    }
}

// ---------------- pass 2: per-bucket CSR build, zero global atomics ----------------

__global__ __launch_bounds__(512) void k_csr(const int* __restrict__ bcur,
                                             const u64* __restrict__ bpair,
                                             int N, int E,
                                             int* __restrict__ row_start,
                                             float* __restrict__ dis,
                                             int* __restrict__ csr_src) {
    __shared__ int cnts[512];
    __shared__ int scanbuf[512];
    __shared__ int cursors[512];
    __shared__ int bb[GBUCKET];
    __shared__ int bbase_s, bcnt_s;
    int g = blockIdx.x;
    int t = threadIdx.x;

    for (int i = t; i < GBUCKET; i += 512) bb[i] = bcur[i];
    cnts[t] = 0;
    __syncthreads();
    if (t == 0) {
        int s = 0;
        for (int k = 0; k < g; ++k) s += bb[k];
        bbase_s = s;
        bcnt_s = bb[g];
    }
    __syncthreads();
    int bbase = bbase_s;
    int cnt   = bcnt_s;

    int lo = (int)(((long long)g * N + GBUCKET - 1) / GBUCKET);
    int hi = (int)(((long long)(g + 1) * N + GBUCKET - 1) / GBUCKET);
    int nn = hi - lo;                                                   // <= 392

    const u64* bp = bpair + (size_t)g * CAP;
    for (int i = t; i < cnt; i += 512) {
        u64 p = __builtin_nontemporal_load(&bp[i]);
        atomicAdd(&cnts[(int)(p >> 32) - lo], 1);                       // LDS atomic
    }
    __syncthreads();

    int v = cnts[t];
    scanbuf[t] = v;
    __syncthreads();
    for (int o = 1; o < 512; o <<= 1) {
        int add = (t >= o) ? scanbuf[t - o] : 0;
        __syncthreads();
        scanbuf[t] += add;
        __syncthreads();
    }
    int excl = scanbuf[t] - v;

    if (t < nn) {
        row_start[lo + t] = bbase + excl;
        dis[lo + t] = rsqrtf((float)v + 1.0f);
    }
    if (g == GBUCKET - 1 && t == 0) row_start[N] = E;
    cursors[t] = excl;
    __syncthreads();

    for (int i = t; i < cnt; i += 512) {
        u64 p = __builtin_nontemporal_load(&bp[i]);
        int d = (int)(p >> 32);
        int s = (int)(p & 0xffffffffu);
        int pos = bbase + atomicAdd(&cursors[d - lo], 1);               // LDS atomic
        csr_src[pos] = s;
    }
}

// ---------------- dense GEMM (layer 1 only): G = (X @ W) * dis[row] ----------------

__global__ __launch_bounds__(256) void k_gemm64(const float* __restrict__ X,
                                                const float* __restrict__ W,
                                                const float* __restrict__ dis,
                                                float* __restrict__ G, int N) {
    __shared__ float ws[64 * 64];
    __shared__ float xs[64 * 64];
    int t = threadIdx.x;
    int row0 = blockIdx.x * 64;
    int nr = N - row0; if (nr > 64) nr = 64;

    const float4* W4 = (const float4*)W;
    float4* ws4 = (float4*)ws;
    for (int i = t; i < 1024; i += 256) ws4[i] = W4[i];
    const float4* X4 = (const float4*)(X + (size_t)row0 * 64);
    float4* xs4 = (float4*)xs;
    for (int i = t; i < nr * 16; i += 256) xs4[i] = X4[i];
    __syncthreads();

    int col = t & 63;
    int rg  = t >> 6;
    float acc[16];
#pragma unroll
    for (int j = 0; j < 16; ++j) acc[j] = 0.0f;

    for (int k4 = 0; k4 < 16; ++k4) {
        float w0 = ws[(k4 * 4 + 0) * 64 + col];
        float w1 = ws[(k4 * 4 + 1) * 64 + col];
        float w2 = ws[(k4 * 4 + 2) * 64 + col];
        float w3 = ws[(k4 * 4 + 3) * 64 + col];
#pragma unroll
        for (int j = 0; j < 16; ++j) {
            float4 xv = xs4[(rg * 16 + j) * 16 + k4];   // wave-uniform broadcast
            acc[j] = fmaf(xv.x, w0, acc[j]);
            acc[j] = fmaf(xv.y, w1, acc[j]);
            acc[j] = fmaf(xv.z, w2, acc[j]);
            acc[j] = fmaf(xv.w, w3, acc[j]);
        }
    }
#pragma unroll
    for (int j = 0; j < 16; ++j) {
        int r = rg * 16 + j;
        if (r < nr) G[(size_t)(row0 + r) * 64 + col] = acc[j] * dis[row0 + r];
    }
}

// ---------------- fused agg + next-layer GEMM (or pooling dot) ----------------
// 512-thread blocks (8 waves) so the 16KB W-tile is amortized over twice the waves:
// occupancy is the whole game for the latency-bound gather (round-12 lesson).
// g prescaled by dis. v_i = relu(dis_i*(sum_j g_j + g_i) + b).
// non-POOL: g_out[i][col] = (sum_k v_i[k] * Wn[k][col]) * dis_i
// POOL:     hdot[i] = dot(v_i, Wn)   (v without relu; Wn = Wl)

template <bool POOL>
__global__ __launch_bounds__(512, 8) void k_fused(const float* __restrict__ g,
                                                  const float* __restrict__ dis,
                                                  const int* __restrict__ row_start,
                                                  const int* __restrict__ csr_src,
                                                  const float* __restrict__ b,
                                                  const float* __restrict__ Wn,
                                                  float* __restrict__ out, int N) {
    __shared__ float ws[64 * 64];
    if (!POOL) {
        const float4* W4 = (const float4*)Wn;
        float4* ws4 = (float4*)ws;
        for (int i = threadIdx.x; i < 1024; i += 512) ws4[i] = W4[i];
        __syncthreads();
    }

    int wave0 = (blockIdx.x * blockDim.x + threadIdx.x) >> 6;
    int nwaves = (gridDim.x * blockDim.x) >> 6;
    int lane = threadIdx.x & 63;
    int sub  = lane >> 4;       // edge slot 0..3
    int q    = lane & 15;       // float4 chunk 0..15
    const float4* g4 = (const float4*)g;

    for (int wid = wave0; wid < N; wid += nwaves) {
        int beg = row_start[wid];
        int end = row_start[wid + 1];

        float4 acc;
        if (sub == 0) acc = g4[(size_t)wid * 16 + q];   // self-loop term, added once
        else          acc = make_float4(0.f, 0.f, 0.f, 0.f);

        int e = beg;
        for (; e + 8 <= end; e += 8) {
            int sA = csr_src[e + sub];
            int sB = csr_src[e + 4 + sub];
            float4 a = g4[(size_t)sA * 16 + q];
            float4 c = g4[(size_t)sB * 16 + q];
            acc.x += a.x; acc.y += a.y; acc.z += a.z; acc.w += a.w;
            acc.x += c.x; acc.y += c.y; acc.z += c.z; acc.w += c.w;
        }
        if (e + 4 <= end) {
            int sA = csr_src[e + sub];
            float4 a = g4[(size_t)sA * 16 + q];
            acc.x += a.x; acc.y += a.y; acc.z += a.z; acc.w += a.w;
            e += 4;
        }
        int rem = end - e;           // 0..3
        if (sub < rem) {
            int sA = csr_src[e + sub];
            float4 a = g4[(size_t)sA * 16 + q];
            acc.x += a.x; acc.y += a.y; acc.z += a.z; acc.w += a.w;
        }

        // reduce across the 4 edge slots; afterwards EVERY lane holds the
        // full sum for its q (replicated across sub groups)
#pragma unroll
        for (int o = 16; o <= 32; o <<= 1) {
            acc.x += __shfl_xor(acc.x, o);
            acc.y += __shfl_xor(acc.y, o);
            acc.z += __shfl_xor(acc.z, o);
            acc.w += __shfl_xor(acc.w, o);
        }

        float d = dis[wid];
        float4 bv = ((const float4*)b)[q];
        float4 v;
        v.x = fmaf(acc.x, d, bv.x);
        v.y = fmaf(acc.y, d, bv.y);
        v.z = fmaf(acc.z, d, bv.z);
        v.w = fmaf(acc.w, d, bv.w);

        if (!POOL) {
            v.x = fmaxf(v.x, 0.f); v.y = fmaxf(v.y, 0.f);
            v.z = fmaxf(v.z, 0.f); v.w = fmaxf(v.w, 0.f);
            // u[col] = sum_k v[k] * Wn[k][col], col = lane; all 64 lanes active
            float u = 0.0f;
#pragma unroll
            for (int kq = 0; kq < 16; ++kq) {
                float vx = __shfl(v.x, kq);
                float vy = __shfl(v.y, kq);
                float vz = __shfl(v.z, kq);
                float vw = __shfl(v.w, kq);
                u = fmaf(vx, ws[(4 * kq + 0) * 64 + lane], u);
                u = fmaf(vy, ws[(4 * kq + 1) * 64 + lane], u);
                u = fmaf(vz, ws[(4 * kq + 2) * 64 + lane], u);
                u = fmaf(vw, ws[(4 * kq + 3) * 64 + lane], u);
            }
            out[(size_t)wid * 64 + lane] = u * d;   // prescale for next layer
        } else {
            if (sub == 0) {
                float4 wl = ((const float4*)Wn)[q];
                float s = v.x * wl.x + v.y * wl.y + v.z * wl.z + v.w * wl.w;
                s += __shfl_xor(s, 1);
                s += __shfl_xor(s, 2);
                s += __shfl_xor(s, 4);
                s += __shfl_xor(s, 8);
                if (q == 0) out[wid] = s;
            }
        }
    }
}

// ---------------- pool finalize: out[g] = mean(hdot over graph g) + bl ----------------

__global__ __launch_bounds__(256) void k_poolfin(const float* __restrict__ hdot,
                                                 const int* __restrict__ batch,
                                                 const float* __restrict__ bl,
                                                 float* __restrict__ out, int N) {
    int g = blockIdx.x;
    int lo = 0, hi = N;
    while (lo < hi) { int m = (lo + hi) >> 1; if (batch[m] < g) lo = m + 1; else hi = m; }
    int start = lo;
    hi = N;
    while (lo < hi) { int m = (lo + hi) >> 1; if (batch[m] <= g) lo = m + 1; else hi = m; }
    int end = lo;

    float part = 0.0f;
    for (int i = start + threadIdx.x; i < end; i += 256)
        part += hdot[i];
    for (int o = 32; o; o >>= 1) part += __shfl_down(part, o);
    __shared__ float ps[4];
    int lane = threadIdx.x & 63;
    int wv = threadIdx.x >> 6;
    if (lane == 0) ps[wv] = part;
    __syncthreads();
    if (threadIdx.x == 0) {
        float s = ps[0] + ps[1] + ps[2] + ps[3];
        float cnt = (float)(end - start);
        out[g] = s / fmaxf(cnt, 1.0f) + bl[0];
    }
}

// ---------------- launcher ----------------

extern "C" void kernel_launch(void* const* d_in, const int* in_sizes, int n_in,
                              void* d_out, int out_size, void* d_ws, size_t ws_size,
                              hipStream_t stream) {
    const float* x     = (const float*)d_in[0];
    const int*   ei    = (const int*)d_in[1];
    const int*   batch = (const int*)d_in[2];
    const float* W1 = (const float*)d_in[3];
    const float* b1 = (const float*)d_in[4];
    const float* W2 = (const float*)d_in[5];
    const float* b2 = (const float*)d_in[6];
    const float* W3 = (const float*)d_in[7];
    const float* b3 = (const float*)d_in[8];
    const float* Wl = (const float*)d_in[9];
    const float* bl = (const float*)d_in[10];
    float* out = (float*)d_out;

    const int N = in_sizes[0] / 64;
    const int E = in_sizes[1] / 2;
    const int* src = ei;
    const int* dst = ei + E;

    char* w = (char*)d_ws;
    auto alloc = [&](size_t bytes) -> void* {
        void* p = (void*)w;
        w += (bytes + 255) & ~(size_t)255;
        return p;
    };
    float* hA        = (float*)alloc((size_t)N * 64 * 4);
    float* hB        = (float*)alloc((size_t)N * 64 * 4);
    int*   csr       = (int*)alloc((size_t)E * 4);
    float* dis       = (float*)alloc((size_t)N * 4);
    int*   row_start = (int*)alloc((size_t)(N + 1) * 4);
    int*   bcur      = (int*)alloc((size_t)GBUCKET * 4);
    float* hdot      = (float*)alloc((size_t)N * 4);

    // buckets overlay hA: GBUCKET * CAP * 8B = 16.8 MB <= 25.6 MB; consumed before gemm1 writes hA
    u64* bpair = (u64*)hA;

    (void)hipMemsetAsync(bcur, 0, (size_t)GBUCKET * 4, stream);

    k_bucket<<<BUCKET_BLOCKS, 256, 0, stream>>>(src, dst, E, N, bcur, bpair);
    k_csr<<<GBUCKET, 512, 0, stream>>>(bcur, bpair, N, E, row_start, dis, csr);

    int gb = (N + 63) / 64;     // gemm blocks
    int ab = 1024;              // fused blocks: 512 threads, grid-stride, 8192 waves

    // layer 1 transform: g1 = (x @ W1) * dis
    k_gemm64<<<gb, 256, 0, stream>>>(x, W1, dis, hA, N);
    // fused: agg(g1)+b1+relu -> h1; g2 = (h1 @ W2)*dis
    k_fused<false><<<ab, 512, 0, stream>>>(hA, dis, row_start, csr, b1, W2, hB, N);
    // fused: agg(g2)+b2+relu -> h2; g3 = (h2 @ W3)*dis
    k_fused<false><<<ab, 512, 0, stream>>>(hB, dis, row_start, csr, b2, W3, hA, N);
    // fused pool: agg(g3)+b3 -> h3; hdot = h3 . Wl
    k_fused<true><<<ab, 512, 0, stream>>>(hA, dis, row_start, csr, b3, Wl, hdot, N);

    // finalize: segmented mean + bias
    k_poolfin<<<NGRAPHS, 256, 0, stream>>>(hdot, batch, bl, out, N);
}

// Round 14
// 368.784 us; speedup vs baseline: 1.5713x; 1.5713x over previous
//
#include <hip/hip_runtime.h>

#define NGRAPHS 256
#define GBUCKET 256
#define CAP 8192          // per-bucket pair capacity; E/G = 6250 expected, >20 sigma margin
#define BUCKET_BLOCKS 512
#define MAXE 16           // per-thread edge cache (E up to 2.09M)

typedef unsigned long long u64;

// ---------------- pass 1: counting-sort edges into 256 dst-range buckets ----------------

__global__ __launch_bounds__(256) void k_bucket(const int* __restrict__ src,
                                                const int* __restrict__ dst,
                                                int E, int N,
                                                int* __restrict__ bcur,
                                                u64* __restrict__ bpair) {
    __shared__ int hist[GBUCKET], base[GBUCKET], cur[GBUCKET];
    int t = threadIdx.x;
    int chunk = (E + gridDim.x - 1) / gridDim.x;
    int s0 = blockIdx.x * chunk;
    int s1 = s0 + chunk; if (s1 > E) s1 = E;
    if (s0 >= E) return;
    for (int i = t; i < GBUCKET; i += 256) hist[i] = 0;
    __syncthreads();

    int dcache[MAXE], scache[MAXE], bcache[MAXE];
#pragma unroll
    for (int u = 0; u < MAXE; ++u) {
        int e = s0 + t + u * 256;
        bool ok = e < s1;
        int d = ok ? __builtin_nontemporal_load(&dst[e]) : -1;
        int s = ok ? __builtin_nontemporal_load(&src[e]) : 0;
        int bkt = ok ? (int)(((long long)d * GBUCKET) / N) : -1;
        dcache[u] = d; scache[u] = s; bcache[u] = bkt;
        if (ok) atomicAdd(&hist[bkt], 1);
    }
    __syncthreads();
    for (int i = t; i < GBUCKET; i += 256) {
        base[i] = atomicAdd(&bcur[i], hist[i]);   // block-level reservation
        cur[i] = 0;
    }
    __syncthreads();
#pragma unroll
    for (int u = 0; u < MAXE; ++u) {
        int bkt = bcache[u];
        if (bkt >= 0) {
            int off = atomicAdd(&cur[bkt], 1);    // LDS atomic
            u64 p = ((u64)(unsigned)dcache[u] << 32) | (u64)(unsigned)scache[u];
            __builtin_nontemporal_store(p, &bpair[(size_t)bkt * CAP + base[bkt] + off]);
        }
    }
}

// ---------------- pass 2: per-bucket CSR build, zero global atomics ----------------

__global__ __launch_bounds__(512) void k_csr(const int* __restrict__ bcur,
                                             const u64* __restrict__ bpair,
                                             int N, int E,
                                             int* __restrict__ row_start,
                                             float* __restrict__ dis,
                                             int* __restrict__ csr_src) {
    __shared__ int cnts[512];
    __shared__ int scanbuf[512];
    __shared__ int cursors[512];
    __shared__ int bb[GBUCKET];
    __shared__ int bbase_s, bcnt_s;
    int g = blockIdx.x;
    int t = threadIdx.x;

    for (int i = t; i < GBUCKET; i += 512) bb[i] = bcur[i];
    cnts[t] = 0;
    __syncthreads();
    if (t == 0) {
        int s = 0;
        for (int k = 0; k < g; ++k) s += bb[k];
        bbase_s = s;
        bcnt_s = bb[g];
    }
    __syncthreads();
    int bbase = bbase_s;
    int cnt   = bcnt_s;

    int lo = (int)(((long long)g * N + GBUCKET - 1) / GBUCKET);
    int hi = (int)(((long long)(g + 1) * N + GBUCKET - 1) / GBUCKET);
    int nn = hi - lo;                                                   // <= 392

    const u64* bp = bpair + (size_t)g * CAP;
    for (int i = t; i < cnt; i += 512) {
        u64 p = __builtin_nontemporal_load(&bp[i]);
        atomicAdd(&cnts[(int)(p >> 32) - lo], 1);                       // LDS atomic
    }
    __syncthreads();

    int v = cnts[t];
    scanbuf[t] = v;
    __syncthreads();
    for (int o = 1; o < 512; o <<= 1) {
        int add = (t >= o) ? scanbuf[t - o] : 0;
        __syncthreads();
        scanbuf[t] += add;
        __syncthreads();
    }
    int excl = scanbuf[t] - v;

    if (t < nn) {
        row_start[lo + t] = bbase + excl;
        dis[lo + t] = rsqrtf((float)v + 1.0f);
    }
    if (g == GBUCKET - 1 && t == 0) row_start[N] = E;
    cursors[t] = excl;
    __syncthreads();

    for (int i = t; i < cnt; i += 512) {
        u64 p = __builtin_nontemporal_load(&bp[i]);
        int d = (int)(p >> 32);
        int s = (int)(p & 0xffffffffu);
        int pos = bbase + atomicAdd(&cursors[d - lo], 1);               // LDS atomic
        csr_src[pos] = s;
    }
}

// ---------------- LDS-free GEMM: G = (X @ W) * dis[row] ----------------
// Lane c holds W[:,c] in 64 VGPRs (coalesced load, L2-resident after first blocks).
// Each wave grid-strides over rows; row pointer is wave-uniform (readfirstlane)
// so xr[k] scalarizes to s_load and the K-loop is pure v_fma(s,v,v): zero LDS ops.

__global__ __launch_bounds__(256) void k_gemm_reg(const float* __restrict__ X,
                                                  const float* __restrict__ W,
                                                  const float* __restrict__ dis,
                                                  float* __restrict__ G, int N) {
    int lane = threadIdx.x & 63;
    int wid = (blockIdx.x * blockDim.x + threadIdx.x) >> 6;
    int nw = (gridDim.x * blockDim.x) >> 6;

    float wreg[64];
#pragma unroll
    for (int k = 0; k < 64; ++k) wreg[k] = W[k * 64 + lane];

    for (int r = wid; r < N; r += nw) {
        int ru = __builtin_amdgcn_readfirstlane(r);
        const float* xr = X + (size_t)ru * 64;
        float a0 = 0.f, a1 = 0.f, a2 = 0.f, a3 = 0.f;
#pragma unroll
        for (int k = 0; k < 64; k += 4) {
            a0 = fmaf(xr[k + 0], wreg[k + 0], a0);
            a1 = fmaf(xr[k + 1], wreg[k + 1], a1);
            a2 = fmaf(xr[k + 2], wreg[k + 2], a2);
            a3 = fmaf(xr[k + 3], wreg[k + 3], a3);
        }
        float a = (a0 + a1) + (a2 + a3);
        G[(size_t)ru * 64 + lane] = a * dis[ru];
    }
}

// ---------------- aggregation: grid-stride, one wave per node, 4 edges in parallel ----------
// g prescaled by dis. out_i = dis_i*(sum_j g_j + g_i) + b, [relu].
// POOL variant (layer 3): skip h write; write hdot[i] = dot(h_i, Wl).

template <bool RELU, bool POOL>
__global__ __launch_bounds__(256) void k_agg(const float* __restrict__ g,
                                             const float* __restrict__ dis,
                                             const int* __restrict__ row_start,
                                             const int* __restrict__ csr_src,
                                             const float* __restrict__ b,
                                             float* __restrict__ out, int N,
                                             const float* __restrict__ Wl,
                                             float* __restrict__ hdot) {
    int wave0 = (blockIdx.x * blockDim.x + threadIdx.x) >> 6;
    int nwaves = (gridDim.x * blockDim.x) >> 6;
    int lane = threadIdx.x & 63;
    int sub  = lane >> 4;       // edge slot 0..3
    int q    = lane & 15;       // float4 chunk 0..15
    const float4* g4 = (const float4*)g;

    for (int wid = wave0; wid < N; wid += nwaves) {
        int beg = row_start[wid];
        int end = row_start[wid + 1];

        float4 acc;
        if (sub == 0) acc = g4[(size_t)wid * 16 + q];   // self-loop term, added once
        else          acc = make_float4(0.f, 0.f, 0.f, 0.f);

        int e = beg;
        for (; e + 8 <= end; e += 8) {
            int sA = csr_src[e + sub];
            int sB = csr_src[e + 4 + sub];
            float4 a = g4[(size_t)sA * 16 + q];
            float4 c = g4[(size_t)sB * 16 + q];
            acc.x += a.x; acc.y += a.y; acc.z += a.z; acc.w += a.w;
            acc.x += c.x; acc.y += c.y; acc.z += c.z; acc.w += c.w;
        }
        if (e + 4 <= end) {
            int sA = csr_src[e + sub];
            float4 a = g4[(size_t)sA * 16 + q];
            acc.x += a.x; acc.y += a.y; acc.z += a.z; acc.w += a.w;
            e += 4;
        }
        int rem = end - e;           // 0..3
        if (sub < rem) {
            int sA = csr_src[e + sub];
            float4 a = g4[(size_t)sA * 16 + q];
            acc.x += a.x; acc.y += a.y; acc.z += a.z; acc.w += a.w;
        }

        // reduce across the 4 edge slots (lanes differing in bits 4,5)
#pragma unroll
        for (int o = 16; o <= 32; o <<= 1) {
            acc.x += __shfl_xor(acc.x, o);
            acc.y += __shfl_xor(acc.y, o);
            acc.z += __shfl_xor(acc.z, o);
            acc.w += __shfl_xor(acc.w, o);
        }

        if (sub == 0) {
            float d = dis[wid];
            float4 bv = ((const float4*)b)[q];
            float4 v;
            v.x = fmaf(acc.x, d, bv.x);
            v.y = fmaf(acc.y, d, bv.y);
            v.z = fmaf(acc.z, d, bv.z);
            v.w = fmaf(acc.w, d, bv.w);
            if (RELU) {
                v.x = fmaxf(v.x, 0.f); v.y = fmaxf(v.y, 0.f);
                v.z = fmaxf(v.z, 0.f); v.w = fmaxf(v.w, 0.f);
            }
            if (POOL) {
                float4 wl = ((const float4*)Wl)[q];
                float s = v.x * wl.x + v.y * wl.y + v.z * wl.z + v.w * wl.w;
                s += __shfl_xor(s, 1);
                s += __shfl_xor(s, 2);
                s += __shfl_xor(s, 4);
                s += __shfl_xor(s, 8);
                if (q == 0) hdot[wid] = s;      // one float per node
            } else {
                ((float4*)out)[(size_t)wid * 16 + q] = v;
            }
        }
    }
}

// ---------------- pool finalize: out[g] = mean(hdot over graph g) + bl ----------------

__global__ __launch_bounds__(256) void k_poolfin(const float* __restrict__ hdot,
                                                 const int* __restrict__ batch,
                                                 const float* __restrict__ bl,
                                                 float* __restrict__ out, int N) {
    int g = blockIdx.x;
    int lo = 0, hi = N;
    while (lo < hi) { int m = (lo + hi) >> 1; if (batch[m] < g) lo = m + 1; else hi = m; }
    int start = lo;
    hi = N;
    while (lo < hi) { int m = (lo + hi) >> 1; if (batch[m] <= g) lo = m + 1; else hi = m; }
    int end = lo;

    float part = 0.0f;
    for (int i = start + threadIdx.x; i < end; i += 256)
        part += hdot[i];
    for (int o = 32; o; o >>= 1) part += __shfl_down(part, o);
    __shared__ float ps[4];
    int lane = threadIdx.x & 63;
    int wv = threadIdx.x >> 6;
    if (lane == 0) ps[wv] = part;
    __syncthreads();
    if (threadIdx.x == 0) {
        float s = ps[0] + ps[1] + ps[2] + ps[3];
        float cnt = (float)(end - start);
        out[g] = s / fmaxf(cnt, 1.0f) + bl[0];
    }
}

// ---------------- launcher ----------------

extern "C" void kernel_launch(void* const* d_in, const int* in_sizes, int n_in,
                              void* d_out, int out_size, void* d_ws, size_t ws_size,
                              hipStream_t stream) {
    const float* x     = (const float*)d_in[0];
    const int*   ei    = (const int*)d_in[1];
    const int*   batch = (const int*)d_in[2];
    const float* W1 = (const float*)d_in[3];
    const float* b1 = (const float*)d_in[4];
    const float* W2 = (const float*)d_in[5];
    const float* b2 = (const float*)d_in[6];
    const float* W3 = (const float*)d_in[7];
    const float* b3 = (const float*)d_in[8];
    const float* Wl = (const float*)d_in[9];
    const float* bl = (const float*)d_in[10];
    float* out = (float*)d_out;

    const int N = in_sizes[0] / 64;
    const int E = in_sizes[1] / 2;
    const int* src = ei;
    const int* dst = ei + E;

    char* w = (char*)d_ws;
    auto alloc = [&](size_t bytes) -> void* {
        void* p = (void*)w;
        w += (bytes + 255) & ~(size_t)255;
        return p;
    };
    float* hA        = (float*)alloc((size_t)N * 64 * 4);
    float* hB        = (float*)alloc((size_t)N * 64 * 4);
    int*   csr       = (int*)alloc((size_t)E * 4);
    float* dis       = (float*)alloc((size_t)N * 4);
    int*   row_start = (int*)alloc((size_t)(N + 1) * 4);
    int*   bcur      = (int*)alloc((size_t)GBUCKET * 4);
    float* hdot      = (float*)alloc((size_t)N * 4);

    // buckets overlay hA: GBUCKET * CAP * 8B = 16.8 MB <= 25.6 MB; consumed before gemm1 writes hA
    u64* bpair = (u64*)hA;

    (void)hipMemsetAsync(bcur, 0, (size_t)GBUCKET * 4, stream);

    k_bucket<<<BUCKET_BLOCKS, 256, 0, stream>>>(src, dst, E, N, bcur, bpair);
    k_csr<<<GBUCKET, 512, 0, stream>>>(bcur, bpair, N, E, row_start, dis, csr);

    int gmb = 2048;             // gemm blocks: grid-stride, 8192 waves
    int ab = 2048;              // agg blocks: grid-stride, 8192 waves

    // layer 1 transform: g1 = (x @ W1) * dis
    k_gemm_reg<<<gmb, 256, 0, stream>>>(x, W1, dis, hA, N);
    k_agg<true, false><<<ab, 256, 0, stream>>>(hA, dis, row_start, csr, b1, hB, N, Wl, nullptr);
    // layer 2
    k_gemm_reg<<<gmb, 256, 0, stream>>>(hB, W2, dis, hA, N);
    k_agg<true, false><<<ab, 256, 0, stream>>>(hA, dis, row_start, csr, b2, hB, N, Wl, nullptr);
    // layer 3 (no relu): fused per-node dot with Wl, no h write
    k_gemm_reg<<<gmb, 256, 0, stream>>>(hB, W3, dis, hA, N);
    k_agg<false, true><<<ab, 256, 0, stream>>>(hA, dis, row_start, csr, b3, nullptr, N, Wl, hdot);

    // finalize: segmented mean + bias
    k_poolfin<<<NGRAPHS, 256, 0, stream>>>(hdot, batch, bl, out, N);
}

// Round 15
// 358.714 us; speedup vs baseline: 1.6154x; 1.0281x over previous
//
#include <hip/hip_runtime.h>

#define NGRAPHS 256
#define GBUCKET 256
#define CAP 8192          // per-bucket pair capacity; E/G = 6250 expected, >20 sigma margin
#define BUCKET_BLOCKS 512
#define MAXE 16           // per-thread edge cache (E up to 2.09M)

typedef unsigned long long u64;
typedef unsigned int u32;

// ---------------- pass 1: counting-sort edges into 256 dst-range buckets ----------------
// Packed pair: (dloc << 17) | src  with dloc = d - bucket_lo (<392), src < 2^17.

__global__ __launch_bounds__(256) void k_bucket(const int* __restrict__ src,
                                                const int* __restrict__ dst,
                                                int E, int N,
                                                int* __restrict__ bcur,
                                                u32* __restrict__ bpair) {
    __shared__ int hist[GBUCKET], base[GBUCKET], cur[GBUCKET];
    int t = threadIdx.x;
    int chunk = (E + gridDim.x - 1) / gridDim.x;
    int s0 = blockIdx.x * chunk;
    int s1 = s0 + chunk; if (s1 > E) s1 = E;
    if (s0 >= E) return;
    for (int i = t; i < GBUCKET; i += 256) hist[i] = 0;
    __syncthreads();

    u32 pcache[MAXE]; int bcache[MAXE];
#pragma unroll
    for (int u = 0; u < MAXE; ++u) {
        int e = s0 + t + u * 256;
        bool ok = e < s1;
        int d = ok ? __builtin_nontemporal_load(&dst[e]) : 0;
        int s = ok ? __builtin_nontemporal_load(&src[e]) : 0;
        int bkt = (int)(((long long)d * GBUCKET) / N);
        int lo  = (int)(((long long)bkt * N + GBUCKET - 1) / GBUCKET);
        pcache[u] = ((u32)(d - lo) << 17) | (u32)s;
        bcache[u] = ok ? bkt : -1;
        if (ok) atomicAdd(&hist[bkt], 1);
    }
    __syncthreads();
    for (int i = t; i < GBUCKET; i += 256) {
        base[i] = atomicAdd(&bcur[i], hist[i]);   // block-level reservation
        cur[i] = 0;
    }
    __syncthreads();
#pragma unroll
    for (int u = 0; u < MAXE; ++u) {
        int bkt = bcache[u];
        if (bkt >= 0) {
            int off = atomicAdd(&cur[bkt], 1);    // LDS atomic
            __builtin_nontemporal_store(pcache[u], &bpair[(size_t)bkt * CAP + base[bkt] + off]);
        }
    }
}

// ---------------- pass 2: per-bucket CSR build, LDS-staged, zero global atomics ----------

__global__ __launch_bounds__(512) void k_csr(const int* __restrict__ bcur,
                                             const u32* __restrict__ bpair,
                                             int N, int E,
                                             int* __restrict__ row_start,
                                             float* __restrict__ dis,
                                             int* __restrict__ csr_src) {
    __shared__ u32 pe[CAP];                 // 32 KB: bucket pairs staged once
    __shared__ int cnts[512];
    __shared__ int scanbuf[512];
    __shared__ int cursors[512];
    __shared__ int bb[GBUCKET];
    __shared__ int bbase_s, bcnt_s;
    int g = blockIdx.x;
    int t = threadIdx.x;

    for (int i = t; i < GBUCKET; i += 512) bb[i] = bcur[i];
    cnts[t] = 0;
    __syncthreads();
    if (t == 0) {
        int s = 0;
        for (int k = 0; k < g; ++k) s += bb[k];
        bbase_s = s;
        bcnt_s = bb[g];
    }
    __syncthreads();
    int bbase = bbase_s;
    int cnt   = bcnt_s;

    int lo = (int)(((long long)g * N + GBUCKET - 1) / GBUCKET);
    int hi = (int)(((long long)(g + 1) * N + GBUCKET - 1) / GBUCKET);
    int nn = hi - lo;                                                   // <= 392

    const u32* bp = bpair + (size_t)g * CAP;
    for (int i = t; i < cnt; i += 512) {
        u32 p = __builtin_nontemporal_load(&bp[i]);
        pe[i] = p;
        atomicAdd(&cnts[p >> 17], 1);                                   // LDS atomic
    }
    __syncthreads();

    int v = cnts[t];
    scanbuf[t] = v;
    __syncthreads();
    for (int o = 1; o < 512; o <<= 1) {
        int add = (t >= o) ? scanbuf[t - o] : 0;
        __syncthreads();
        scanbuf[t] += add;
        __syncthreads();
    }
    int excl = scanbuf[t] - v;

    if (t < nn) {
        row_start[lo + t] = bbase + excl;
        dis[lo + t] = rsqrtf((float)v + 1.0f);
    }
    if (g == GBUCKET - 1 && t == 0) row_start[N] = E;
    cursors[t] = excl;
    __syncthreads();

    for (int i = t; i < cnt; i += 512) {
        u32 p = pe[i];                                                  // LDS read
        int dloc = p >> 17;
        int s = (int)(p & 0x1FFFFu);
        int pos = bbase + atomicAdd(&cursors[dloc], 1);                 // LDS atomic
        csr_src[pos] = s;
    }
}

// ---------------- LDS-free GEMM: G = (X @ W) * dis[row] ----------------

__global__ __launch_bounds__(256) void k_gemm_reg(const float* __restrict__ X,
                                                  const float* __restrict__ W,
                                                  const float* __restrict__ dis,
                                                  float* __restrict__ G, int N) {
    int lane = threadIdx.x & 63;
    int wid = (blockIdx.x * blockDim.x + threadIdx.x) >> 6;
    int nw = (gridDim.x * blockDim.x) >> 6;

    float wreg[64];
#pragma unroll
    for (int k = 0; k < 64; ++k) wreg[k] = W[k * 64 + lane];

    for (int r = wid; r < N; r += nw) {
        int ru = __builtin_amdgcn_readfirstlane(r);
        const float* xr = X + (size_t)ru * 64;
        float a0 = 0.f, a1 = 0.f, a2 = 0.f, a3 = 0.f;
#pragma unroll
        for (int k = 0; k < 64; k += 4) {
            a0 = fmaf(xr[k + 0], wreg[k + 0], a0);
            a1 = fmaf(xr[k + 1], wreg[k + 1], a1);
            a2 = fmaf(xr[k + 2], wreg[k + 2], a2);
            a3 = fmaf(xr[k + 3], wreg[k + 3], a3);
        }
        float a = (a0 + a1) + (a2 + a3);
        G[(size_t)ru * 64 + lane] = a * dis[ru];
    }
}

// ---------------- aggregation: grid-stride, one wave per node, 4 edges in parallel ----------

template <bool RELU, bool POOL>
__global__ __launch_bounds__(256) void k_agg(const float* __restrict__ g,
                                             const float* __restrict__ dis,
                                             const int* __restrict__ row_start,
                                             const int* __restrict__ csr_src,
                                             const float* __restrict__ b,
                                             float* __restrict__ out, int N,
                                             const float* __restrict__ Wl,
                                             float* __restrict__ hdot) {
    int wave0 = (blockIdx.x * blockDim.x + threadIdx.x) >> 6;
    int nwaves = (gridDim.x * blockDim.x) >> 6;
    int lane = threadIdx.x & 63;
    int sub  = lane >> 4;       // edge slot 0..3
    int q    = lane & 15;       // float4 chunk 0..15
    const float4* g4 = (const float4*)g;

    for (int wid = wave0; wid < N; wid += nwaves) {
        int beg = row_start[wid];
        int end = row_start[wid + 1];

        float4 acc;
        if (sub == 0) acc = g4[(size_t)wid * 16 + q];   // self-loop term, added once
        else          acc = make_float4(0.f, 0.f, 0.f, 0.f);

        int e = beg;
        for (; e + 8 <= end; e += 8) {
            int sA = csr_src[e + sub];
            int sB = csr_src[e + 4 + sub];
            float4 a = g4[(size_t)sA * 16 + q];
            float4 c = g4[(size_t)sB * 16 + q];
            acc.x += a.x; acc.y += a.y; acc.z += a.z; acc.w += a.w;
            acc.x += c.x; acc.y += c.y; acc.z += c.z; acc.w += c.w;
        }
        if (e + 4 <= end) {
            int sA = csr_src[e + sub];
            float4 a = g4[(size_t)sA * 16 + q];
            acc.x += a.x; acc.y += a.y; acc.z += a.z; acc.w += a.w;
            e += 4;
        }
        int rem = end - e;           // 0..3
        if (sub < rem) {
            int sA = csr_src[e + sub];
            float4 a = g4[(size_t)sA * 16 + q];
            acc.x += a.x; acc.y += a.y; acc.z += a.z; acc.w += a.w;
        }

        // reduce across the 4 edge slots (lanes differing in bits 4,5)
#pragma unroll
        for (int o = 16; o <= 32; o <<= 1) {
            acc.x += __shfl_xor(acc.x, o);
            acc.y += __shfl_xor(acc.y, o);
            acc.z += __shfl_xor(acc.z, o);
            acc.w += __shfl_xor(acc.w, o);
        }

        if (sub == 0) {
            float d = dis[wid];
            float4 bv = ((const float4*)b)[q];
            float4 v;
            v.x = fmaf(acc.x, d, bv.x);
            v.y = fmaf(acc.y, d, bv.y);
            v.z = fmaf(acc.z, d, bv.z);
            v.w = fmaf(acc.w, d, bv.w);
            if (RELU) {
                v.x = fmaxf(v.x, 0.f); v.y = fmaxf(v.y, 0.f);
                v.z = fmaxf(v.z, 0.f); v.w = fmaxf(v.w, 0.f);
            }
            if (POOL) {
                float4 wl = ((const float4*)Wl)[q];
                float s = v.x * wl.x + v.y * wl.y + v.z * wl.z + v.w * wl.w;
                s += __shfl_xor(s, 1);
                s += __shfl_xor(s, 2);
                s += __shfl_xor(s, 4);
                s += __shfl_xor(s, 8);
                if (q == 0) hdot[wid] = s;      // one float per node
            } else {
                ((float4*)out)[(size_t)wid * 16 + q] = v;
            }
        }
    }
}

// ---------------- pool finalize: out[g] = mean(hdot over graph g) + bl ----------------

__global__ __launch_bounds__(256) void k_poolfin(const float* __restrict__ hdot,
                                                 const int* __restrict__ batch,
                                                 const float* __restrict__ bl,
                                                 float* __restrict__ out, int N) {
    int g = blockIdx.x;
    int lo = 0, hi = N;
    while (lo < hi) { int m = (lo + hi) >> 1; if (batch[m] < g) lo = m + 1; else hi = m; }
    int start = lo;
    hi = N;
    while (lo < hi) { int m = (lo + hi) >> 1; if (batch[m] <= g) lo = m + 1; else hi = m; }
    int end = lo;

    float part = 0.0f;
    for (int i = start + threadIdx.x; i < end; i += 256)
        part += hdot[i];
    for (int o = 32; o; o >>= 1) part += __shfl_down(part, o);
    __shared__ float ps[4];
    int lane = threadIdx.x & 63;
    int wv = threadIdx.x >> 6;
    if (lane == 0) ps[wv] = part;
    __syncthreads();
    if (threadIdx.x == 0) {
        float s = ps[0] + ps[1] + ps[2] + ps[3];
        float cnt = (float)(end - start);
        out[g] = s / fmaxf(cnt, 1.0f) + bl[0];
    }
}

// ---------------- launcher ----------------

extern "C" void kernel_launch(void* const* d_in, const int* in_sizes, int n_in,
                              void* d_out, int out_size, void* d_ws, size_t ws_size,
                              hipStream_t stream) {
    const float* x     = (const float*)d_in[0];
    const int*   ei    = (const int*)d_in[1];
    const int*   batch = (const int*)d_in[2];
    const float* W1 = (const float*)d_in[3];
    const float* b1 = (const float*)d_in[4];
    const float* W2 = (const float*)d_in[5];
    const float* b2 = (const float*)d_in[6];
    const float* W3 = (const float*)d_in[7];
    const float* b3 = (const float*)d_in[8];
    const float* Wl = (const float*)d_in[9];
    const float* bl = (const float*)d_in[10];
    float* out = (float*)d_out;

    const int N = in_sizes[0] / 64;
    const int E = in_sizes[1] / 2;
    const int* src = ei;
    const int* dst = ei + E;

    char* w = (char*)d_ws;
    auto alloc = [&](size_t bytes) -> void* {
        void* p = (void*)w;
        w += (bytes + 255) & ~(size_t)255;
        return p;
    };
    float* hA        = (float*)alloc((size_t)N * 64 * 4);
    float* hB        = (float*)alloc((size_t)N * 64 * 4);
    int*   csr       = (int*)alloc((size_t)E * 4);
    float* dis       = (float*)alloc((size_t)N * 4);
    int*   row_start = (int*)alloc((size_t)(N + 1) * 4);
    int*   bcur      = (int*)alloc((size_t)GBUCKET * 4);
    float* hdot      = (float*)alloc((size_t)N * 4);

    // packed buckets overlay hA: GBUCKET * CAP * 4B = 8.4 MB <= 25.6 MB
    u32* bpair = (u32*)hA;

    (void)hipMemsetAsync(bcur, 0, (size_t)GBUCKET * 4, stream);

    k_bucket<<<BUCKET_BLOCKS, 256, 0, stream>>>(src, dst, E, N, bcur, bpair);
    k_csr<<<GBUCKET, 512, 0, stream>>>(bcur, bpair, N, E, row_start, dis, csr);

    int gmb = 2048;             // gemm blocks: grid-stride, 8192 waves
    int ab = 2048;              // agg blocks: grid-stride, 8192 waves

    // layer 1 transform: g1 = (x @ W1) * dis
    k_gemm_reg<<<gmb, 256, 0, stream>>>(x, W1, dis, hA, N);
    k_agg<true, false><<<ab, 256, 0, stream>>>(hA, dis, row_start, csr, b1, hB, N, Wl, nullptr);
    // layer 2
    k_gemm_reg<<<gmb, 256, 0, stream>>>(hB, W2, dis, hA, N);
    k_agg<true, false><<<ab, 256, 0, stream>>>(hA, dis, row_start, csr, b2, hB, N, Wl, nullptr);
    // layer 3 (no relu): fused per-node dot with Wl, no h write
    k_gemm_reg<<<gmb, 256, 0, stream>>>(hB, W3, dis, hA, N);
    k_agg<false, true><<<ab, 256, 0, stream>>>(hA, dis, row_start, csr, b3, nullptr, N, Wl, hdot);

    // finalize: segmented mean + bias
    k_poolfin<<<NGRAPHS, 256, 0, stream>>>(hdot, batch, bl, out, N);
}